// Round 1
// baseline (649.641 us; speedup 1.0000x reference)
//
#include <hip/hip_runtime.h>
#include <cstdint>

#define BSZ 4
#define NN 256
#define DXC 256
#define DFFC 1024
#define ROWS (BSZ*NN)   // 1024

// ---------------------------------------------------------------------------
// gemm64: C[M,Nn] = epi(A[M,K] @ B[K,Nn] + bias)
// BM=BN=64, BK=32, 256 threads, 4x4 outputs/thread.
// A staged TRANSPOSED in LDS (As[k][m]) so the inner loop is 2x ds_read_b128
// per 16 FMAs. Double-buffered LDS, ONE barrier per K-tile, register prefetch
// issued before the compute loop (latency hides under 1024 cyc of FMAs).
// EPI: 0 = +bias; 1 = (+bias)*mask[row]; 2 = relu(+bias)
// blockIdx.z selects (B,bias,C) triple (fuses Q/K/V into one launch).
// ---------------------------------------------------------------------------
template <int EPI>
__global__ __launch_bounds__(256) void gemm64(
    const float* __restrict__ A,
    const float* __restrict__ B0, const float* __restrict__ B1,
    const float* __restrict__ B2,
    const float* __restrict__ bias0, const float* __restrict__ bias1,
    const float* __restrict__ bias2,
    float* __restrict__ C0, float* __restrict__ C1, float* __restrict__ C2,
    const float* __restrict__ mask,
    int M, int Nn, int K)
{
    const float* B = B0; const float* bias = bias0; float* C = C0;
    if (blockIdx.z == 1) { B = B1; bias = bias1; C = C1; }
    if (blockIdx.z == 2) { B = B2; bias = bias2; C = C2; }

    // stride 68: rows 16B-aligned (68*4=272), row base shifts 4 banks/row.
    // A-read: 4 distinct addrs broadcast (free). B-read: 16 distinct, 2-way (free).
    __shared__ float As[2][32][68];   // [buf][k][m]
    __shared__ float Bs[2][32][68];   // [buf][k][n]

    const int tid  = threadIdx.x;
    const int row0 = blockIdx.y * 64;
    const int col0 = blockIdx.x * 64;
    const int tx4 = (tid & 15) * 4;   // n within tile
    const int ty4 = (tid >> 4) * 4;   // m within tile

    // staging lanes
    const int ar = tid >> 3;          // 0..31 (A rows, two halves)
    const int ak = (tid & 7) * 4;     // 0..28
    const int br = tid >> 4;          // 0..15 (B rows, two halves)
    const int bn = (tid & 15) * 4;    // 0..60

    const float* Ap  = A + (size_t)(row0 + ar) * K + ak;
    const float* Ap2 = A + (size_t)(row0 + 32 + ar) * K + ak;
    const float* Bp  = B + (size_t)br * Nn + col0 + bn;
    const float* Bp2 = B + (size_t)(br + 16) * Nn + col0 + bn;

    float4 a0 = *(const float4*)Ap;
    float4 a1 = *(const float4*)Ap2;
    float4 b0 = *(const float4*)Bp;
    float4 b1 = *(const float4*)Bp2;

    float acc[4][4] = {};

    // stage tile 0
    As[0][ak+0][ar] = a0.x; As[0][ak+1][ar] = a0.y;
    As[0][ak+2][ar] = a0.z; As[0][ak+3][ar] = a0.w;
    As[0][ak+0][ar+32] = a1.x; As[0][ak+1][ar+32] = a1.y;
    As[0][ak+2][ar+32] = a1.z; As[0][ak+3][ar+32] = a1.w;
    *(float4*)&Bs[0][br][bn]      = b0;
    *(float4*)&Bs[0][br+16][bn]   = b1;
    __syncthreads();

    const int nt = K >> 5;
    for (int t = 0; t < nt; ++t) {
        const int cur = t & 1, nxt = cur ^ 1;
        const bool more = (t + 1 < nt);
        if (more) {   // prefetch next tile into registers (overlaps compute)
            const int k0 = (t + 1) << 5;
            a0 = *(const float4*)(Ap + k0);
            a1 = *(const float4*)(Ap2 + k0);
            b0 = *(const float4*)(Bp + (size_t)k0 * Nn);
            b1 = *(const float4*)(Bp2 + (size_t)k0 * Nn);
        }
        #pragma unroll
        for (int k = 0; k < 32; ++k) {
            const float4 av = *(const float4*)&As[cur][k][ty4];
            const float4 bv = *(const float4*)&Bs[cur][k][tx4];
            acc[0][0] = fmaf(av.x, bv.x, acc[0][0]);
            acc[0][1] = fmaf(av.x, bv.y, acc[0][1]);
            acc[0][2] = fmaf(av.x, bv.z, acc[0][2]);
            acc[0][3] = fmaf(av.x, bv.w, acc[0][3]);
            acc[1][0] = fmaf(av.y, bv.x, acc[1][0]);
            acc[1][1] = fmaf(av.y, bv.y, acc[1][1]);
            acc[1][2] = fmaf(av.y, bv.z, acc[1][2]);
            acc[1][3] = fmaf(av.y, bv.w, acc[1][3]);
            acc[2][0] = fmaf(av.z, bv.x, acc[2][0]);
            acc[2][1] = fmaf(av.z, bv.y, acc[2][1]);
            acc[2][2] = fmaf(av.z, bv.z, acc[2][2]);
            acc[2][3] = fmaf(av.z, bv.w, acc[2][3]);
            acc[3][0] = fmaf(av.w, bv.x, acc[3][0]);
            acc[3][1] = fmaf(av.w, bv.y, acc[3][1]);
            acc[3][2] = fmaf(av.w, bv.z, acc[3][2]);
            acc[3][3] = fmaf(av.w, bv.w, acc[3][3]);
        }
        if (more) {
            // write next tile; readers of buffer nxt all passed previous barrier
            As[nxt][ak+0][ar] = a0.x; As[nxt][ak+1][ar] = a0.y;
            As[nxt][ak+2][ar] = a0.z; As[nxt][ak+3][ar] = a0.w;
            As[nxt][ak+0][ar+32] = a1.x; As[nxt][ak+1][ar+32] = a1.y;
            As[nxt][ak+2][ar+32] = a1.z; As[nxt][ak+3][ar+32] = a1.w;
            *(float4*)&Bs[nxt][br][bn]    = b0;
            *(float4*)&Bs[nxt][br+16][bn] = b1;
            __syncthreads();
        }
    }

    // epilogue: 4 rows x float4
    const int c0 = col0 + tx4;
    const float4 bi = *(const float4*)(bias + c0);
    #pragma unroll
    for (int i = 0; i < 4; ++i) {
        const int r = row0 + ty4 + i;
        float4 v = make_float4(acc[i][0] + bi.x, acc[i][1] + bi.y,
                               acc[i][2] + bi.z, acc[i][3] + bi.w);
        if constexpr (EPI == 1) {
            const float m = mask[r];
            v.x *= m; v.y *= m; v.z *= m; v.w *= m;
        } else if constexpr (EPI == 2) {
            v.x = fmaxf(v.x, 0.f); v.y = fmaxf(v.y, 0.f);
            v.z = fmaxf(v.z, 0.f); v.w = fmaxf(v.w, 0.f);
        }
        *(float4*)&C[(size_t)r * Nn + c0] = v;
    }
}

// ---------------------------------------------------------------------------
// Attention core: one block per (b,i), 512 threads = 8 waves (4 blk/CU = 32
// waves/CU -> full occupancy; was 16). Each wave owns j = wv (mod 8); body
// processes TWO j per iteration with all 8 float4 loads issued up front for
// memory-level parallelism. Streaming e_add/e_mul is the mandatory traffic.
// ---------------------------------------------------------------------------
__global__ __launch_bounds__(512) void attn_kernel(
    const float* __restrict__ Qb, const float* __restrict__ Kb, const float* __restrict__ Vb,
    const float* __restrict__ e_add, const float* __restrict__ e_mul,
    const float* __restrict__ y_x_add, const float* __restrict__ y_x_mul,
    const float* __restrict__ nmask,
    float* __restrict__ nXi)
{
    const int row  = blockIdx.x;       // b*N + i
    const int b    = row >> 8;
    const int tid  = threadIdx.x;
    const int wv   = tid >> 6;         // 0..7 (j phase)
    const int lane = tid & 63;
    const int hd   = lane << 2;

    const float mi = nmask[row];
    float4 q = *(const float4*)(Qb + (size_t)row * DXC + hd);
    const float inv = 0.17677669529663687f;  // 1/sqrt(32)
    q.x *= inv; q.y *= inv; q.z *= inv; q.w *= inv;

    const float* ea_p = e_add + (size_t)row * NN * DXC + hd;
    const float* em_p = e_mul + (size_t)row * NN * DXC + hd;
    const float* kp = Kb + (size_t)(b << 8) * DXC + hd;
    const float* vp = Vb + (size_t)(b << 8) * DXC + hd;
    const float* mp = nmask + (b << 8);

    float s0=0.f,s1=0.f,s2=0.f,s3=0.f;   // softmax denominators
    float o0=0.f,o1=0.f,o2=0.f,o3=0.f;   // sum p*V

    for (int j = wv; j < NN; j += 16) {
        const int j2 = j + 8;
        const float mjA = mp[j];            // wave-uniform
        const float mjB = mp[j2];
        const size_t oA = (size_t)j  * DXC;
        const size_t oB = (size_t)j2 * DXC;
        const float4 kA  = *(const float4*)(kp  + oA);
        const float4 vA  = *(const float4*)(vp  + oA);
        const float4 emA = *(const float4*)(em_p + oA);
        const float4 eaA = *(const float4*)(ea_p + oA);
        const float4 kB  = *(const float4*)(kp  + oB);
        const float4 vB  = *(const float4*)(vp  + oB);
        const float4 emB = *(const float4*)(em_p + oB);
        const float4 eaB = *(const float4*)(ea_p + oB);

        const float eeA = mi * mjA;
        const float eeB = mi * mjB;
        float y0 = (q.x*kA.x) * (emA.x*eeA + 1.f) + eaA.x*eeA;
        float y1 = (q.y*kA.y) * (emA.y*eeA + 1.f) + eaA.y*eeA;
        float y2 = (q.z*kA.z) * (emA.z*eeA + 1.f) + eaA.z*eeA;
        float y3 = (q.w*kA.w) * (emA.w*eeA + 1.f) + eaA.w*eeA;
        float z0 = (q.x*kB.x) * (emB.x*eeB + 1.f) + eaB.x*eeB;
        float z1 = (q.y*kB.y) * (emB.y*eeB + 1.f) + eaB.y*eeB;
        float z2 = (q.z*kB.z) * (emB.z*eeB + 1.f) + eaB.z*eeB;
        float z3 = (q.w*kB.w) * (emB.w*eeB + 1.f) + eaB.w*eeB;
        if (!(mjA > 0.f)) { y0 = y1 = y2 = y3 = -1e30f; }   // exp -> 0
        if (!(mjB > 0.f)) { z0 = z1 = z2 = z3 = -1e30f; }

        const float pA0 = __expf(y0), pA1 = __expf(y1), pA2 = __expf(y2), pA3 = __expf(y3);
        const float pB0 = __expf(z0), pB1 = __expf(z1), pB2 = __expf(z2), pB3 = __expf(z3);
        s0 += pA0 + pB0; s1 += pA1 + pB1; s2 += pA2 + pB2; s3 += pA3 + pB3;
        o0 = fmaf(pA0, vA.x, fmaf(pB0, vB.x, o0));
        o1 = fmaf(pA1, vA.y, fmaf(pB1, vB.y, o1));
        o2 = fmaf(pA2, vA.z, fmaf(pB2, vB.z, o2));
        o3 = fmaf(pA3, vA.w, fmaf(pB3, vB.w, o3));
    }

    __shared__ float sl[8][256];
    __shared__ float sa[8][256];
    *(float4*)&sl[wv][hd] = make_float4(s0, s1, s2, s3);
    *(float4*)&sa[wv][hd] = make_float4(o0, o1, o2, o3);
    __syncthreads();

    if (tid < 256) {
        const int c = tid;  // channel
        float L = 0.f, Acc = 0.f;
        #pragma unroll
        for (int w = 0; w < 8; ++w) { L += sl[w][c]; Acc += sa[w][c]; }
        const float wV = Acc / L;
        const float yxa = y_x_add[b * DXC + c];
        const float yxm = y_x_mul[b * DXC + c];
        nXi[(size_t)row * DXC + c] = yxa + (yxm + 1.f) * wV;
    }
}

// ---------------------------------------------------------------------------
// LayerNorm: one block per row, 256 threads = 256 channels.
// ---------------------------------------------------------------------------
__global__ __launch_bounds__(256) void ln_kernel(
    const float* __restrict__ base, const float* __restrict__ delta,
    const float* __restrict__ g, const float* __restrict__ be,
    float* __restrict__ out)
{
    const int row = blockIdx.x, t = threadIdx.x;
    const size_t idx = (size_t)row * DXC + t;
    const float s = base[idx] + delta[idx];
    __shared__ float red[8];
    float sum = s, sq = s * s;
    #pragma unroll
    for (int o = 32; o > 0; o >>= 1) { sum += __shfl_down(sum, o); sq += __shfl_down(sq, o); }
    if ((t & 63) == 0) { red[t >> 6] = sum; red[4 + (t >> 6)] = sq; }
    __syncthreads();
    sum = red[0] + red[1] + red[2] + red[3];
    sq  = red[4] + red[5] + red[6] + red[7];
    const float mean = sum * (1.f / DXC);
    const float var  = sq * (1.f / DXC) - mean * mean;
    const float r = rsqrtf(var + 1e-5f);
    out[idx] = (s - mean) * r * g[t] + be[t];
}

// ---------------------------------------------------------------------------
extern "C" void kernel_launch(void* const* d_in, const int* in_sizes, int n_in,
                              void* d_out, int out_size, void* d_ws, size_t ws_size,
                              hipStream_t stream)
{
    const float* X       = (const float*)d_in[0];
    const float* e_add   = (const float*)d_in[1];
    const float* e_mul   = (const float*)d_in[2];
    const float* y_x_add = (const float*)d_in[3];
    const float* y_x_mul = (const float*)d_in[4];
    const float* nmask   = (const float*)d_in[5];
    const float* Wq = (const float*)d_in[6];
    const float* bq = (const float*)d_in[7];
    const float* Wk = (const float*)d_in[8];
    const float* bk = (const float*)d_in[9];
    const float* Wv = (const float*)d_in[10];
    const float* bv = (const float*)d_in[11];
    const float* Wo = (const float*)d_in[12];
    const float* bo = (const float*)d_in[13];
    const float* W1 = (const float*)d_in[14];
    const float* b1 = (const float*)d_in[15];
    const float* W2 = (const float*)d_in[16];
    const float* b2 = (const float*)d_in[17];
    const float* g1 = (const float*)d_in[18];
    const float* be1= (const float*)d_in[19];
    const float* g2 = (const float*)d_in[20];
    const float* be2= (const float*)d_in[21];

    float* ws  = (float*)d_ws;
    float* Qb  = ws + 0 * 262144;
    float* Kb  = ws + 1 * 262144;
    float* Vb  = ws + 2 * 262144;
    float* nXi = ws + 3 * 262144;
    float* nXo = ws + 4 * 262144;
    float* X1b = ws + 5 * 262144;
    float* ffo = ws + 6 * 262144;
    float* hb  = ws + 7 * 262144;

    // Q,K,V = (X @ W + b) * mask  (one launch, z selects q/k/v)
    gemm64<1><<<dim3(DXC/64, ROWS/64, 3), 256, 0, stream>>>(
        X, Wq, Wk, Wv, bq, bk, bv, Qb, Kb, Vb, nmask, ROWS, DXC, DXC);

    // attention core (streams e_add/e_mul)
    attn_kernel<<<dim3(ROWS), 512, 0, stream>>>(
        Qb, Kb, Vb, e_add, e_mul, y_x_add, y_x_mul, nmask, nXi);

    // newX = (nXi @ Wo + bo) * mask
    gemm64<1><<<dim3(DXC/64, ROWS/64, 1), 256, 0, stream>>>(
        nXi, Wo, Wo, Wo, bo, bo, bo, nXo, nXo, nXo, nmask, ROWS, DXC, DXC);

    // X1 = LN(X + newX)
    ln_kernel<<<dim3(ROWS), 256, 0, stream>>>(X, nXo, g1, be1, X1b);

    // h = relu(X1 @ W1 + b1)
    gemm64<2><<<dim3(DFFC/64, ROWS/64, 1), 256, 0, stream>>>(
        X1b, W1, W1, W1, b1, b1, b1, hb, hb, hb, nullptr, ROWS, DFFC, DXC);

    // ffo = h @ W2 + b2
    gemm64<0><<<dim3(DXC/64, ROWS/64, 1), 256, 0, stream>>>(
        hb, W2, W2, W2, b2, b2, b2, ffo, ffo, ffo, nullptr, ROWS, DXC, DFFC);

    // out = LN(X1 + ffo)
    ln_kernel<<<dim3(ROWS), 256, 0, stream>>>(X1b, ffo, g2, be2, (float*)d_out);
}